// Round 16
// baseline (139.234 us; speedup 1.0000x reference)
//
#include <hip/hip_runtime.h>
#include <hip/hip_fp16.h>
#include <cstdint>

#define NCH 128   // IN_CH == OUT_CH == 128
#define NSLICE 8  // 8 col-slices of 16 ch: 100000*16*2B = 3.2 MB/slice < 4 MB L2/XCD

typedef short short8v __attribute__((ext_vector_type(8)));
typedef unsigned short ushort4v __attribute__((ext_vector_type(4)));
typedef float f32x4  __attribute__((ext_vector_type(4)));

// f32 -> bf16 bits, round-to-nearest-even
static __device__ __forceinline__ short f2bf(float f) {
    unsigned u = __float_as_uint(f);
    u += 0x7FFFu + ((u >> 16) & 1u);
    return (short)(u >> 16);
}
static __device__ __forceinline__ unsigned short f2h(float f) {
    return __half_as_ushort(__float2half(f));
}
static __device__ __forceinline__ float h2f(unsigned short u) {
    return __half2float(__ushort_as_half(u));
}

// L2-direct gather (r12: neutral vs plain load; part of champion config)
static __device__ __forceinline__ ushort4v gather8_l2(const unsigned short* p) {
    unsigned long long v = __hip_atomic_load(
        reinterpret_cast<const unsigned long long*>(p),
        __ATOMIC_RELAXED, __HIP_MEMORY_SCOPE_AGENT);
    return __builtin_bit_cast(ushort4v, v);
}

// ---------------------------------------------------------------------------
// prep: a = softmax(attn_weights); Wpb[o][d] = bf16(W[o][d] * a[d])
// ---------------------------------------------------------------------------
__global__ __launch_bounds__(128)
void prep_kernel(const float* __restrict__ aw,
                 const float* __restrict__ W,
                 short* __restrict__ Wpb) {
    __shared__ float sa[NCH];
    const int t = threadIdx.x;
    const int o = blockIdx.x;
    sa[t] = aw[t];
    __syncthreads();
    float m = -1e30f;
#pragma unroll
    for (int d = 0; d < NCH; ++d) m = fmaxf(m, sa[d]);
    float s = 0.f;
#pragma unroll
    for (int d = 0; d < NCH; ++d) s += expf(sa[d] - m);
    const float av = expf(sa[t] - m) / s;
    Wpb[o * NCH + t] = f2bf(W[o * NCH + t] * av);
}

// ---------------------------------------------------------------------------
// node GEMM v3 (byte-identical to r15 champion-equivalent)
// ---------------------------------------------------------------------------
__global__ __launch_bounds__(256)
void node_gemm_mfma(const float* __restrict__ X,
                    const short* __restrict__ Wpb,
                    const float* __restrict__ bias,
                    unsigned short* __restrict__ Ys, int M) {
    __shared__ short sW[NCH * NCH];          // 32 KB, swizzled 16B chunks
    const int t = threadIdx.x;

    for (int it = 0; it < 8; ++it) {
        const int j   = it * 256 + t;
        const int row = j >> 4;
        const int cc  = j & 15;
        const int scc = cc ^ (row & 7);
        *reinterpret_cast<short8v*>(&sW[row * NCH + scc * 8]) =
            *reinterpret_cast<const short8v*>(Wpb + (size_t)j * 8);
    }
    __syncthreads();

    const int wave = t >> 6;
    const int lane = t & 63;
    const int r    = lane & 15;
    const int kb   = lane >> 4;

    const int nbase = blockIdx.x * 256 + wave * 64;

    short8v b[4][4];
    int node[4];
#pragma unroll
    for (int ng = 0; ng < 4; ++ng) {
        node[ng] = nbase + ng * 16 + r;
        const int nodec = node[ng] < M ? node[ng] : M - 1;
        const float* xr = X + (size_t)nodec * NCH;
#pragma unroll
        for (int ks = 0; ks < 4; ++ks) {
            const float4 f0 = *reinterpret_cast<const float4*>(xr + ks * 32 + kb * 8);
            const float4 f1 = *reinterpret_cast<const float4*>(xr + ks * 32 + kb * 8 + 4);
            short8v v;
            v[0] = f2bf(f0.x); v[1] = f2bf(f0.y); v[2] = f2bf(f0.z); v[3] = f2bf(f0.w);
            v[4] = f2bf(f1.x); v[5] = f2bf(f1.y); v[6] = f2bf(f1.z); v[7] = f2bf(f1.w);
            b[ng][ks] = v;
        }
    }

#pragma unroll
    for (int tile = 0; tile < 8; ++tile) {
        f32x4 acc[4];
#pragma unroll
        for (int ng = 0; ng < 4; ++ng) acc[ng] = (f32x4){0.f, 0.f, 0.f, 0.f};
        const int row = tile * 16 + r;
#pragma unroll
        for (int ks = 0; ks < 4; ++ks) {
            const int cc = ks * 4 + kb;
            const short8v a = *reinterpret_cast<const short8v*>(
                &sW[row * NCH + (cc ^ (row & 7)) * 8]);
            acc[0] = __builtin_amdgcn_mfma_f32_16x16x32_bf16(a, b[0][ks], acc[0], 0, 0, 0);
            acc[1] = __builtin_amdgcn_mfma_f32_16x16x32_bf16(a, b[1][ks], acc[1], 0, 0, 0);
            acc[2] = __builtin_amdgcn_mfma_f32_16x16x32_bf16(a, b[2][ks], acc[2], 0, 0, 0);
            acc[3] = __builtin_amdgcn_mfma_f32_16x16x32_bf16(a, b[3][ks], acc[3], 0, 0, 0);
        }
        const float4 vb = *reinterpret_cast<const float4*>(bias + tile * 16 + kb * 4);
#pragma unroll
        for (int ng = 0; ng < 4; ++ng) {
            if (node[ng] < M) {
                ushort4v h;
                h[0] = f2h(acc[ng][0] + 0.5f * vb.x);
                h[1] = f2h(acc[ng][1] + 0.5f * vb.y);
                h[2] = f2h(acc[ng][2] + 0.5f * vb.z);
                h[3] = f2h(acc[ng][3] + 0.5f * vb.w);
                *reinterpret_cast<ushort4v*>(
                    Ys + (size_t)tile * M * 16 + (size_t)node[ng] * 16 + kb * 4) = h;
            }
        }
    }
}

// ---------------------------------------------------------------------------
// sliced edge kernel (byte-identical to r12 champion)
// ---------------------------------------------------------------------------
__global__ __launch_bounds__(256)
void edge_out_sliced(const unsigned short* __restrict__ Ys,
                     const int* __restrict__ ei,
                     float* __restrict__ out, int E, int M) {
    const unsigned bid = blockIdx.x;
    const int slice = bid & (NSLICE - 1);
    const int eblk  = bid >> 3;
    const int t  = threadIdx.x;
    const int cl = t & 3;
    const int e0 = eblk * 256 + (t >> 2);      // edges e0 + k*64, k=0..3

    const unsigned short* base = Ys + (size_t)slice * M * 16 + cl * 4;

    int s[4], g[4];
#pragma unroll
    for (int k = 0; k < 4; ++k) {
        const int e = e0 + k * 64;
        const int ec = e < E ? e : 0;
        s[k] = ei[ec];
        g[k] = ei[E + ec];
    }
    ushort4v hs[4], ht[4];
#pragma unroll
    for (int k = 0; k < 4; ++k) {
        hs[k] = gather8_l2(base + (size_t)s[k] * 16);
        ht[k] = gather8_l2(base + (size_t)g[k] * 16);
    }
#pragma unroll
    for (int k = 0; k < 4; ++k) {
        const int e = e0 + k * 64;
        if (e < E) {
            f32x4 r;
            r[0] = fmaxf(h2f(hs[k][0]) + h2f(ht[k][0]), 0.f);
            r[1] = fmaxf(h2f(hs[k][1]) + h2f(ht[k][1]), 0.f);
            r[2] = fmaxf(h2f(hs[k][2]) + h2f(ht[k][2]), 0.f);
            r[3] = fmaxf(h2f(hs[k][3]) + h2f(ht[k][3]), 0.f);
            f32x4* dst = reinterpret_cast<f32x4*>(
                out + (size_t)e * NCH + slice * 16 + cl * 4);
            __builtin_nontemporal_store(r, dst);
        }
    }
}

// ---------------------------------------------------------------------------
// fallback (only if ws too small): fully self-contained direct fp32 edge GEMM
// ---------------------------------------------------------------------------
__global__ __launch_bounds__(256)
void direct_edge_kernel(const float* __restrict__ X,
                        const int* __restrict__ ei,
                        const float* __restrict__ aw,
                        const float* __restrict__ W,
                        const float* __restrict__ bias,
                        float* __restrict__ out, int E) {
    __shared__ float sW[NCH][NCH + 1];
    __shared__ float sa[NCH];
    __shared__ float sE[8][NCH + 4];
    const int t = threadIdx.x;
    if (t < NCH) sa[t] = aw[t];
    __syncthreads();
    float m = -1e30f;
#pragma unroll
    for (int d = 0; d < NCH; ++d) m = fmaxf(m, sa[d]);
    float ssum = 0.f;
#pragma unroll
    for (int d = 0; d < NCH; ++d) ssum += expf(sa[d] - m);
    const float av = (t < NCH) ? expf(sa[t] - m) / ssum : 0.f;
    __syncthreads();
    if (t < NCH) sa[t] = av;
    __syncthreads();
    for (int i = t; i < NCH * 32; i += 256) {
        const int o = i >> 5, q = i & 31;
        float4 v = reinterpret_cast<const float4*>(W)[o * 32 + q];
        sW[o][q * 4 + 0] = v.x * sa[q * 4 + 0];
        sW[o][q * 4 + 1] = v.y * sa[q * 4 + 1];
        sW[o][q * 4 + 2] = v.z * sa[q * 4 + 2];
        sW[o][q * 4 + 3] = v.w * sa[q * 4 + 3];
    }
    __syncthreads();
    const int le = t >> 5, q = t & 31;
    for (int e0 = blockIdx.x * 8; e0 < E; e0 += gridDim.x * 8) {
        const int e = e0 + le;
        if (e < E) {
            const int s = ei[e];
            const int g = ei[E + e];
            const float4 vs = reinterpret_cast<const float4*>(X)[(size_t)s * 32 + q];
            const float4 vt = reinterpret_cast<const float4*>(X)[(size_t)g * 32 + q];
            sE[le][q * 4 + 0] = vs.x + vt.x;
            sE[le][q * 4 + 1] = vs.y + vt.y;
            sE[le][q * 4 + 2] = vs.z + vt.z;
            sE[le][q * 4 + 3] = vs.w + vt.w;
        }
        __syncthreads();
        if (e < E) {
            float a0 = 0.f, a1 = 0.f, a2 = 0.f, a3 = 0.f;
            const int o = q * 4;
#pragma unroll 4
            for (int d = 0; d < NCH; ++d) {
                const float x = sE[le][d];
                a0 += x * sW[o + 0][d];
                a1 += x * sW[o + 1][d];
                a2 += x * sW[o + 2][d];
                a3 += x * sW[o + 3][d];
            }
            float4 r;
            r.x = fmaxf(a0 + bias[o + 0], 0.f);
            r.y = fmaxf(a1 + bias[o + 1], 0.f);
            r.z = fmaxf(a2 + bias[o + 2], 0.f);
            r.w = fmaxf(a3 + bias[o + 3], 0.f);
            reinterpret_cast<float4*>(out)[(size_t)e * 32 + q] = r;
        }
        __syncthreads();
    }
}

// ---------------------------------------------------------------------------
// MEASUREMENT ROUND 2: launches = prep, gemm, gemm, gemm, edge.
// Duplicated gemms are idempotent (same inputs -> same Ys). With r15's
// p+g+e = 106.1:  g = (dur - 106.1 - 2L)/2, L ~ 1-3us launch overhead.
// ---------------------------------------------------------------------------
extern "C" void kernel_launch(void* const* d_in, const int* in_sizes, int n_in,
                              void* d_out, int out_size, void* d_ws, size_t ws_size,
                              hipStream_t stream) {
    const float* X    = (const float*)d_in[0];   // [100000,128] f32
    const int*   ei   = (const int*)d_in[1];     // [2,625000] int32
    const float* aw   = (const float*)d_in[2];   // [128] f32
    const float* W    = (const float*)d_in[3];   // [128,128] f32
    const float* bias = (const float*)d_in[4];   // [128] f32
    float* out = (float*)d_out;

    const int M = in_sizes[0] / NCH;             // 100000 nodes
    const int E = in_sizes[1] / 2;               // 625000 edges

    const size_t y_off   = 65536;                                    // Wpb (32KB) + pad
    const size_t y_bytes = (size_t)M * NCH * sizeof(unsigned short); // 25.6 MB sliced

    if (ws_size >= y_off + y_bytes) {
        short* Wpb = (short*)d_ws;
        unsigned short* Ys = (unsigned short*)((char*)d_ws + y_off);
        prep_kernel<<<NCH, 128, 0, stream>>>(aw, W, Wpb);
        node_gemm_mfma<<<(M + 255) / 256, 256, 0, stream>>>(X, Wpb, bias, Ys, M);
        node_gemm_mfma<<<(M + 255) / 256, 256, 0, stream>>>(X, Wpb, bias, Ys, M);
        node_gemm_mfma<<<(M + 255) / 256, 256, 0, stream>>>(X, Wpb, bias, Ys, M);
        const int eblks = (E + 255) / 256;
        edge_out_sliced<<<eblks * NSLICE, 256, 0, stream>>>(Ys, ei, out, E, M);
    } else {
        int grid = (E + 7) / 8;
        if (grid > 32768) grid = 32768;
        direct_edge_kernel<<<grid, 256, 0, stream>>>(X, ei, aw, W, bias, out, E);
    }
}

// Round 17
// 105.599 us; speedup vs baseline: 1.3185x; 1.3185x over previous
//
#include <hip/hip_runtime.h>
#include <hip/hip_fp16.h>
#include <cstdint>

#define NCH 128   // IN_CH == OUT_CH == 128
#define NSLICE 8  // 8 col-slices of 16 ch: 100000*16*2B = 3.2 MB/slice < 4 MB L2/XCD

typedef short short8v __attribute__((ext_vector_type(8)));
typedef unsigned short ushort4v __attribute__((ext_vector_type(4)));
typedef float f32x4  __attribute__((ext_vector_type(4)));

// f32 -> bf16 bits, round-to-nearest-even
static __device__ __forceinline__ short f2bf(float f) {
    unsigned u = __float_as_uint(f);
    u += 0x7FFFu + ((u >> 16) & 1u);
    return (short)(u >> 16);
}
static __device__ __forceinline__ unsigned short f2h(float f) {
    return __half_as_ushort(__float2half(f));
}
static __device__ __forceinline__ float h2f(unsigned short u) {
    return __half2float(__ushort_as_half(u));
}

// L2-direct gather (r12: neutral vs plain load; part of champion config)
static __device__ __forceinline__ ushort4v gather8_l2(const unsigned short* p) {
    unsigned long long v = __hip_atomic_load(
        reinterpret_cast<const unsigned long long*>(p),
        __ATOMIC_RELAXED, __HIP_MEMORY_SCOPE_AGENT);
    return __builtin_bit_cast(ushort4v, v);
}

// ---------------------------------------------------------------------------
// node GEMM v4: prep FUSED (r16 measurement: gemm ~15us vs 13us floor; the
// remaining system win is launch/pass elimination).
// Per block: softmax(aw) in LDS (bit-identical math to the old prep kernel),
// then stage Wp = bf16(W * a) directly into swizzled LDS from W (f32).
// MFMA body identical to r15: 4 node-groups/wave, swizzled ds_read_b128,
// bias/2 fold, packed 8B stores into the sliced fp16 layout.
// ---------------------------------------------------------------------------
__global__ __launch_bounds__(256)
void node_gemm_fused(const float* __restrict__ X,
                     const float* __restrict__ aw,
                     const float* __restrict__ W,
                     const float* __restrict__ bias,
                     unsigned short* __restrict__ Ys, int M) {
    __shared__ short sW[NCH * NCH];          // 32 KB, swizzled 16B chunks
    __shared__ float sa[NCH];                // raw aw, then reused read-only
    __shared__ float sA[NCH];                // softmax(aw)
    const int t = threadIdx.x;

    if (t < NCH) sa[t] = aw[t];
    __syncthreads();
    // per-thread full softmax over 128 (bit-identical to old prep kernel)
    {
        float m = -1e30f;
#pragma unroll
        for (int d = 0; d < NCH; ++d) m = fmaxf(m, sa[d]);
        float s = 0.f;
#pragma unroll
        for (int d = 0; d < NCH; ++d) s += expf(sa[d] - m);
        if (t < NCH) sA[t] = expf(sa[t] - m) / s;
    }
    __syncthreads();

    // stage Wp -> LDS: 2048 chunks of 16B (8 cols each); col swizzle cc^=row&7
    for (int it = 0; it < 8; ++it) {
        const int j   = it * 256 + t;
        const int row = j >> 4;
        const int cc  = j & 15;
        const int scc = cc ^ (row & 7);
        const float* wr = W + (size_t)row * NCH + cc * 8;
        const float4 f0 = *reinterpret_cast<const float4*>(wr);
        const float4 f1 = *reinterpret_cast<const float4*>(wr + 4);
        const int d0 = cc * 8;
        short8v v;
        v[0] = f2bf(f0.x * sA[d0 + 0]); v[1] = f2bf(f0.y * sA[d0 + 1]);
        v[2] = f2bf(f0.z * sA[d0 + 2]); v[3] = f2bf(f0.w * sA[d0 + 3]);
        v[4] = f2bf(f1.x * sA[d0 + 4]); v[5] = f2bf(f1.y * sA[d0 + 5]);
        v[6] = f2bf(f1.z * sA[d0 + 6]); v[7] = f2bf(f1.w * sA[d0 + 7]);
        *reinterpret_cast<short8v*>(&sW[row * NCH + scc * 8]) = v;
    }
    __syncthreads();

    const int wave = t >> 6;
    const int lane = t & 63;
    const int r    = lane & 15;
    const int kb   = lane >> 4;

    const int nbase = blockIdx.x * 256 + wave * 64;

    short8v b[4][4];
    int node[4];
#pragma unroll
    for (int ng = 0; ng < 4; ++ng) {
        node[ng] = nbase + ng * 16 + r;
        const int nodec = node[ng] < M ? node[ng] : M - 1;   // stores guarded
        const float* xr = X + (size_t)nodec * NCH;
#pragma unroll
        for (int ks = 0; ks < 4; ++ks) {
            const float4 f0 = *reinterpret_cast<const float4*>(xr + ks * 32 + kb * 8);
            const float4 f1 = *reinterpret_cast<const float4*>(xr + ks * 32 + kb * 8 + 4);
            short8v v;
            v[0] = f2bf(f0.x); v[1] = f2bf(f0.y); v[2] = f2bf(f0.z); v[3] = f2bf(f0.w);
            v[4] = f2bf(f1.x); v[5] = f2bf(f1.y); v[6] = f2bf(f1.z); v[7] = f2bf(f1.w);
            b[ng][ks] = v;
        }
    }

#pragma unroll
    for (int tile = 0; tile < 8; ++tile) {
        f32x4 acc[4];
#pragma unroll
        for (int ng = 0; ng < 4; ++ng) acc[ng] = (f32x4){0.f, 0.f, 0.f, 0.f};
        const int row = tile * 16 + r;
#pragma unroll
        for (int ks = 0; ks < 4; ++ks) {
            const int cc = ks * 4 + kb;
            const short8v a = *reinterpret_cast<const short8v*>(
                &sW[row * NCH + (cc ^ (row & 7)) * 8]);
            acc[0] = __builtin_amdgcn_mfma_f32_16x16x32_bf16(a, b[0][ks], acc[0], 0, 0, 0);
            acc[1] = __builtin_amdgcn_mfma_f32_16x16x32_bf16(a, b[1][ks], acc[1], 0, 0, 0);
            acc[2] = __builtin_amdgcn_mfma_f32_16x16x32_bf16(a, b[2][ks], acc[2], 0, 0, 0);
            acc[3] = __builtin_amdgcn_mfma_f32_16x16x32_bf16(a, b[3][ks], acc[3], 0, 0, 0);
        }
        const float4 vb = *reinterpret_cast<const float4*>(bias + tile * 16 + kb * 4);
#pragma unroll
        for (int ng = 0; ng < 4; ++ng) {
            if (node[ng] < M) {
                ushort4v h;
                h[0] = f2h(acc[ng][0] + 0.5f * vb.x);
                h[1] = f2h(acc[ng][1] + 0.5f * vb.y);
                h[2] = f2h(acc[ng][2] + 0.5f * vb.z);
                h[3] = f2h(acc[ng][3] + 0.5f * vb.w);
                *reinterpret_cast<ushort4v*>(
                    Ys + (size_t)tile * M * 16 + (size_t)node[ng] * 16 + kb * 4) = h;
            }
        }
    }
}

// ---------------------------------------------------------------------------
// sliced edge kernel (byte-identical to r12 champion; 7 falsified theories say
// it is at its request-rate/write equilibrium — do not touch)
// ---------------------------------------------------------------------------
__global__ __launch_bounds__(256)
void edge_out_sliced(const unsigned short* __restrict__ Ys,
                     const int* __restrict__ ei,
                     float* __restrict__ out, int E, int M) {
    const unsigned bid = blockIdx.x;
    const int slice = bid & (NSLICE - 1);
    const int eblk  = bid >> 3;
    const int t  = threadIdx.x;
    const int cl = t & 3;
    const int e0 = eblk * 256 + (t >> 2);      // edges e0 + k*64, k=0..3

    const unsigned short* base = Ys + (size_t)slice * M * 16 + cl * 4;

    int s[4], g[4];
#pragma unroll
    for (int k = 0; k < 4; ++k) {
        const int e = e0 + k * 64;
        const int ec = e < E ? e : 0;
        s[k] = ei[ec];
        g[k] = ei[E + ec];
    }
    ushort4v hs[4], ht[4];
#pragma unroll
    for (int k = 0; k < 4; ++k) {
        hs[k] = gather8_l2(base + (size_t)s[k] * 16);
        ht[k] = gather8_l2(base + (size_t)g[k] * 16);
    }
#pragma unroll
    for (int k = 0; k < 4; ++k) {
        const int e = e0 + k * 64;
        if (e < E) {
            f32x4 r;
            r[0] = fmaxf(h2f(hs[k][0]) + h2f(ht[k][0]), 0.f);
            r[1] = fmaxf(h2f(hs[k][1]) + h2f(ht[k][1]), 0.f);
            r[2] = fmaxf(h2f(hs[k][2]) + h2f(ht[k][2]), 0.f);
            r[3] = fmaxf(h2f(hs[k][3]) + h2f(ht[k][3]), 0.f);
            f32x4* dst = reinterpret_cast<f32x4*>(
                out + (size_t)e * NCH + slice * 16 + cl * 4);
            __builtin_nontemporal_store(r, dst);
        }
    }
}

// ---------------------------------------------------------------------------
// fallback (only if ws too small): fully self-contained direct fp32 edge GEMM
// ---------------------------------------------------------------------------
__global__ __launch_bounds__(256)
void direct_edge_kernel(const float* __restrict__ X,
                        const int* __restrict__ ei,
                        const float* __restrict__ aw,
                        const float* __restrict__ W,
                        const float* __restrict__ bias,
                        float* __restrict__ out, int E) {
    __shared__ float sW[NCH][NCH + 1];
    __shared__ float sa[NCH];
    __shared__ float sE[8][NCH + 4];
    const int t = threadIdx.x;
    if (t < NCH) sa[t] = aw[t];
    __syncthreads();
    float m = -1e30f;
#pragma unroll
    for (int d = 0; d < NCH; ++d) m = fmaxf(m, sa[d]);
    float ssum = 0.f;
#pragma unroll
    for (int d = 0; d < NCH; ++d) ssum += expf(sa[d] - m);
    const float av = (t < NCH) ? expf(sa[t] - m) / ssum : 0.f;
    __syncthreads();
    if (t < NCH) sa[t] = av;
    __syncthreads();
    for (int i = t; i < NCH * 32; i += 256) {
        const int o = i >> 5, q = i & 31;
        float4 v = reinterpret_cast<const float4*>(W)[o * 32 + q];
        sW[o][q * 4 + 0] = v.x * sa[q * 4 + 0];
        sW[o][q * 4 + 1] = v.y * sa[q * 4 + 1];
        sW[o][q * 4 + 2] = v.z * sa[q * 4 + 2];
        sW[o][q * 4 + 3] = v.w * sa[q * 4 + 3];
    }
    __syncthreads();
    const int le = t >> 5, q = t & 31;
    for (int e0 = blockIdx.x * 8; e0 < E; e0 += gridDim.x * 8) {
        const int e = e0 + le;
        if (e < E) {
            const int s = ei[e];
            const int g = ei[E + e];
            const float4 vs = reinterpret_cast<const float4*>(X)[(size_t)s * 32 + q];
            const float4 vt = reinterpret_cast<const float4*>(X)[(size_t)g * 32 + q];
            sE[le][q * 4 + 0] = vs.x + vt.x;
            sE[le][q * 4 + 1] = vs.y + vt.y;
            sE[le][q * 4 + 2] = vs.z + vt.z;
            sE[le][q * 4 + 3] = vs.w + vt.w;
        }
        __syncthreads();
        if (e < E) {
            float a0 = 0.f, a1 = 0.f, a2 = 0.f, a3 = 0.f;
            const int o = q * 4;
#pragma unroll 4
            for (int d = 0; d < NCH; ++d) {
                const float x = sE[le][d];
                a0 += x * sW[o + 0][d];
                a1 += x * sW[o + 1][d];
                a2 += x * sW[o + 2][d];
                a3 += x * sW[o + 3][d];
            }
            float4 r;
            r.x = fmaxf(a0 + bias[o + 0], 0.f);
            r.y = fmaxf(a1 + bias[o + 1], 0.f);
            r.z = fmaxf(a2 + bias[o + 2], 0.f);
            r.w = fmaxf(a3 + bias[o + 3], 0.f);
            reinterpret_cast<float4*>(out)[(size_t)e * 32 + q] = r;
        }
        __syncthreads();
    }
}

// ---------------------------------------------------------------------------
extern "C" void kernel_launch(void* const* d_in, const int* in_sizes, int n_in,
                              void* d_out, int out_size, void* d_ws, size_t ws_size,
                              hipStream_t stream) {
    const float* X    = (const float*)d_in[0];   // [100000,128] f32
    const int*   ei   = (const int*)d_in[1];     // [2,625000] int32
    const float* aw   = (const float*)d_in[2];   // [128] f32
    const float* W    = (const float*)d_in[3];   // [128,128] f32
    const float* bias = (const float*)d_in[4];   // [128] f32
    float* out = (float*)d_out;

    const int M = in_sizes[0] / NCH;             // 100000 nodes
    const int E = in_sizes[1] / 2;               // 625000 edges

    const size_t y_bytes = (size_t)M * NCH * sizeof(unsigned short); // 25.6 MB sliced

    if (ws_size >= y_bytes) {
        unsigned short* Ys = (unsigned short*)d_ws;
        node_gemm_fused<<<(M + 255) / 256, 256, 0, stream>>>(X, aw, W, bias, Ys, M);
        const int eblks = (E + 255) / 256;
        edge_out_sliced<<<eblks * NSLICE, 256, 0, stream>>>(Ys, ei, out, E, M);
    } else {
        int grid = (E + 7) / 8;
        if (grid > 32768) grid = 32768;
        direct_edge_kernel<<<grid, 256, 0, stream>>>(X, ei, aw, W, bias, out, E);
    }
}